// Round 13
// baseline (42.698 us; speedup 1.0000x reference)
//
#include <hip/hip_runtime.h>
#include <hip/hip_fp16.h>
#include <math.h>

#define BB 16
#define CC 3
#define HH 512
#define WW 512
#define HW (HH * WW)
#define RAD 5
#define SEGV 16
#define NSEG (HH / SEGV)            // 32 segments per image
#define NSTRIP 5                    // 5 overlapping 128-col strips, 116 valid each
#define STRIPW 116
#define NTASK (BB * NSEG * NSTRIP)  // 2560 wave-tasks
#define NBLK (NTASK / 2)            // 1280 blocks (2 waves each)
#define NITER (SEGV + 2 * RAD)      // 26 row iterations
#define DEPTH 5                     // LDS row-ring slots (read slot != write slot)

__device__ __forceinline__ __half2 shfl_h2(__half2 v, int src) {
    union { __half2 h; int i; } u;
    u.h = v;
    u.i = __shfl(u.i, src);
    return u.h;
}

// async global -> LDS, 4 B per lane, dest = wave-uniform base + lane*4
#define GLOAD(G, L) __builtin_amdgcn_global_load_lds( \
    (const __attribute__((address_space(1))) void*)(G), \
    (__attribute__((address_space(3))) void*)(L), 4, 0, 0)

// R7/R12 math body; loads replaced by a depth-4 global_load_lds pipeline
// with counted vmcnt (never 0 in steady state). Per wave: 5-slot LDS ring
// of staged rows (6 channels x 128 floats), ds_read_b64 consumption.
__global__ __launch_bounds__(128) void fused_lds(
    const float* __restrict__ pred, const float* __restrict__ target,
    float* __restrict__ ws_sq, float* __restrict__ ws_cos)
{
    __shared__ float lds[2][DEPTH][6][128];   // 30 KB
    __shared__ float red[4];
    const int tid  = threadIdx.x;
    const int wave = tid >> 6, lane = tid & 63;

    // bijective XCD-contiguous swizzle (1280 % 8 == 0)
    const int bid = (int)blockIdx.x;
    const int swz = (bid & 7) * (NBLK / 8) + (bid >> 3);

    const int task  = swz * 2 + wave;
    const int img   = task / (NSEG * NSTRIP);
    const int rem   = task % (NSEG * NSTRIP);
    const int seg   = rem / NSTRIP;
    const int strip = rem - seg * NSTRIP;

    const int y0      = seg * SEGV;
    const int colbase = strip * STRIPW - 6;
    const int col0    = colbase + lane * 2;
    const float mx    = (col0 >= 0 && col0 < WW) ? 1.f : 0.f;
    const bool  vout  = (lane >= 3) && (lane <= 60) && (col0 < WW);

    const float* predB = pred   + (long)img * (CC * HW);
    const float* targB = target + (long)img * (CC * HW);

    // per-lane clamped source columns for the two half-rows (row-invariant)
    const int vcolA = min(max(colbase + lane, 0), WW - 1);
    const int vcolB = min(max(colbase + 64 + lane, 0), WW - 1);

#define ISSUE(S, Y) do { \
        const int  yc_ = min(max((Y), 0), HH - 1); \
        const long ro_ = (long)yc_ * WW; \
        GLOAD(predB + ro_            + vcolA, &lds[wave][S][0][0]);  \
        GLOAD(predB + ro_            + vcolB, &lds[wave][S][0][64]); \
        GLOAD(predB + HW + ro_       + vcolA, &lds[wave][S][1][0]);  \
        GLOAD(predB + HW + ro_       + vcolB, &lds[wave][S][1][64]); \
        GLOAD(predB + 2 * HW + ro_   + vcolA, &lds[wave][S][2][0]);  \
        GLOAD(predB + 2 * HW + ro_   + vcolB, &lds[wave][S][2][64]); \
        GLOAD(targB + ro_            + vcolA, &lds[wave][S][3][0]);  \
        GLOAD(targB + ro_            + vcolB, &lds[wave][S][3][64]); \
        GLOAD(targB + HW + ro_       + vcolA, &lds[wave][S][4][0]);  \
        GLOAD(targB + HW + ro_       + vcolB, &lds[wave][S][4][64]); \
        GLOAD(targB + 2 * HW + ro_   + vcolA, &lds[wave][S][5][0]);  \
        GLOAD(targB + 2 * HW + ro_   + vcolB, &lds[wave][S][5][64]); \
    } while (0)

    // prologue: rows 0..3 in flight (48 loads)
    ISSUE(0, y0 - RAD + 0);
    ISSUE(1, y0 - RAD + 1);
    ISSUE(2, y0 - RAD + 2);
    ISSUE(3, y0 - RAD + 3);

    __half2 ring0[11], ring1[11], ringT[11];   // (hd0,hp0), (hd1,hp1), (ht0,ht1)
    float Sd0=0.f, Sd1=0.f, Sp0=0.f, Sp1=0.f, St0=0.f, St1=0.f;
    float sq = 0.f, cosacc = 0.f;

    #pragma unroll
    for (int it = 0; it < NITER; ++it) {
        // counted vmcnt: row `it` landed, 3 rows (36 loads) stay in flight
        if (it < NITER - 3)       asm volatile("s_waitcnt vmcnt(36)" ::: "memory");
        else if (it == NITER - 3) asm volatile("s_waitcnt vmcnt(24)" ::: "memory");
        else if (it == NITER - 2) asm volatile("s_waitcnt vmcnt(12)" ::: "memory");
        else                      asm volatile("s_waitcnt vmcnt(0)"  ::: "memory");

        const int slot = it % DEPTH;           // static under full unroll
        const float2 p0 = *(const float2*)&lds[wave][slot][0][2 * lane];
        const float2 p1 = *(const float2*)&lds[wave][slot][1][2 * lane];
        const float2 p2 = *(const float2*)&lds[wave][slot][2][2 * lane];
        const float2 t0 = *(const float2*)&lds[wave][slot][3][2 * lane];
        const float2 t1 = *(const float2*)&lds[wave][slot][4][2 * lane];
        const float2 t2 = *(const float2*)&lds[wave][slot][5][2 * lane];

        // refill: row it+4 into slot (it+4)%DEPTH (!= current read slot)
        if (it + 4 < NITER) ISSUE((it + 4) % DEPTH, y0 - RAD + it + 4);

        const int y = y0 - RAD + it;
        const float msk = (y >= 0 && y < HH) ? mx : 0.f;

        // per-pixel dot/pp/tt, masked (zero padding outside image)
        const float ad = (p0.x*t0.x + p1.x*t1.x + p2.x*t2.x) * msk;
        const float bd = (p0.y*t0.y + p1.y*t1.y + p2.y*t2.y) * msk;
        const float ap = (p0.x*p0.x + p1.x*p1.x + p2.x*p2.x) * msk;
        const float bp = (p0.y*p0.y + p1.y*p1.y + p2.y*p2.y) * msk;
        const float at = (t0.x*t0.x + t1.x*t1.x + t2.x*t2.x) * msk;
        const float bt = (t0.y*t0.y + t1.y*t1.y + t2.y*t2.y) * msk;

        // PSNR squared error from the maps: sum_c (p-t)^2 = pp - 2*dot + tt
        if (it >= RAD && it < RAD + SEGV && vout) {
            sq += (ap + at - 2.f * ad) + (bp + bt - 2.f * bd);
        }

        // ---- horizontal 11-window (R7 tree) ----
        __half2 h0dp, h1dp;
        {
            const __half2 Pk = __floats2half2_rn(ad + bd, ap + bp);
            const __half2 Ak = __floats2half2_rn(ad, ap);
            const __half2 Bk = __floats2half2_rn(bd, bp);
            const __half2 u1 = __hadd2(Pk, shfl_h2(Pk, lane + 1));
            const __half2 u2 = __hadd2(u1, shfl_h2(u1, lane + 2));
            const __half2 u3 = __hadd2(u2, shfl_h2(Pk, lane + 4));
            const __half2 S5 = shfl_h2(u3, lane - 2);
            h0dp = __hadd2(shfl_h2(Bk, lane - 3), S5);
            h1dp = __hadd2(S5, shfl_h2(Ak, lane + 3));
        }
        __half2 hT;
        {
            const float pr = at + bt;
            const float u1 = pr + __shfl(pr, lane + 1);
            const float u2 = u1 + __shfl(u1, lane + 2);
            const float u3 = u2 + __shfl(pr, lane + 4);
            const float S5 = __shfl(u3, lane - 2);
            hT = __floats2half2_rn(__shfl(bt, lane - 3) + S5,
                                   S5 + __shfl(at, lane + 3));
        }

        // accumulate the QUANTIZED values -> ring subtract cancels exactly
        const float2 f0 = __half22float2(h0dp);
        const float2 f1 = __half22float2(h1dp);
        const float2 fT = __half22float2(hT);
        Sd0 += f0.x; Sp0 += f0.y;
        Sd1 += f1.x; Sp1 += f1.y;
        St0 += fT.x; St1 += fT.y;

        if (it >= 10) {
            if (vout) {
                cosacc += Sd0 * rsqrtf(fmaxf(Sp0 * St0, 1e-20f));
                cosacc += Sd1 * rsqrtf(fmaxf(Sp1 * St1, 1e-20f));
            }
            const float2 o0 = __half22float2(ring0[(it + 1) % 11]);
            const float2 o1 = __half22float2(ring1[(it + 1) % 11]);
            const float2 oT = __half22float2(ringT[(it + 1) % 11]);
            Sd0 -= o0.x; Sp0 -= o0.y;
            Sd1 -= o1.x; Sp1 -= o1.y;
            St0 -= oT.x; St1 -= oT.y;
        }
        ring0[it % 11] = h0dp;
        ring1[it % 11] = h1dp;
        ringT[it % 11] = hT;
    }

    // wave reduce -> block partials
    #pragma unroll
    for (int o = 32; o > 0; o >>= 1) {
        cosacc += __shfl_down(cosacc, o);
        sq     += __shfl_down(sq, o);
    }
    if (lane == 0) { red[wave] = cosacc; red[wave + 2] = sq; }
    __syncthreads();
    if (tid == 0) {
        ws_cos[swz] = red[0] + red[1];
        ws_sq [swz] = red[2] + red[3];
    }
}

// ---------------- finalize: 1280 sq + 1280 cos partials ----------------
__global__ __launch_bounds__(256) void finalize4(
    const float* __restrict__ ws_sq, const float* __restrict__ ws_cos,
    float* __restrict__ out)
{
    __shared__ float sq_b[16];
    __shared__ float cred[4];
    const int tid = threadIdx.x;

    // sq: 80 partials per image; 16 threads/image, 5 values each
    const int b = tid >> 4, j = tid & 15;
    float s = 0.f;
    #pragma unroll
    for (int k = 0; k < 5; ++k) s += ws_sq[b * 80 + j * 5 + k];
    #pragma unroll
    for (int o = 8; o > 0; o >>= 1) s += __shfl_down(s, o, 16);
    if (j == 0) sq_b[b] = s;

    float c = 0.f;
    #pragma unroll
    for (int k = 0; k < 5; ++k) c += ws_cos[tid + 256 * k];
    #pragma unroll
    for (int o = 32; o > 0; o >>= 1) c += __shfl_down(c, o);
    if ((tid & 63) == 0) cred[tid >> 6] = c;
    __syncthreads();

    if (tid == 0) {
        const float csum = cred[0] + cred[1] + cred[2] + cred[3];
        const float scale = 4.342944819032518f;   // 10 / ln(10)
        float lsum = 0.f;
        for (int bb = 0; bb < 16; ++bb)
            lsum += logf(sq_b[bb] / (float)(CC * HW) + 1e-8f);
        out[0] = scale * (lsum / (float)BB) + (1.f - csum / (float)(BB * HW));
    }
}

extern "C" void kernel_launch(void* const* d_in, const int* in_sizes, int n_in,
                              void* d_out, int out_size, void* d_ws, size_t ws_size,
                              hipStream_t stream)
{
    const float* pred   = (const float*)d_in[0];
    const float* target = (const float*)d_in[1];

    float* ws_sq  = (float*)d_ws;                        // 1280 floats
    float* ws_cos = (float*)((char*)d_ws + 8192);        // 1280 floats

    fused_lds<<<dim3(NBLK), 128, 0, stream>>>(pred, target, ws_sq, ws_cos);
    finalize4<<<1, 256, 0, stream>>>(ws_sq, ws_cos, (float*)d_out);
}

// Round 14
// 33.918 us; speedup vs baseline: 1.2589x; 1.2589x over previous
//
#include <hip/hip_runtime.h>
#include <hip/hip_fp16.h>
#include <math.h>

#define BB 16
#define CC 3
#define HH 512
#define WW 512
#define HW (HH * WW)
#define RAD 5
#define SEGV 16
#define NSEG (HH / SEGV)            // 32 segments per image
#define NSTRIP 5                    // 5 overlapping 128-col strips, 116 valid each
#define STRIPW 116
#define NTASK (BB * NSEG * NSTRIP)  // 2560 wave-tasks
#define NBLK (NTASK / 2)            // 1280 blocks (2 waves each)
#define NITER (SEGV + 2 * RAD)      // 26 row iterations

// ---- DPP wave-shift helpers (VALU pipe, no DS) ----
// WAVE_SHL1 (0x130): lane i <- lane i-1 (data moves toward higher lanes)
// WAVE_SHR1 (0x138): lane i <- lane i+1
// bound_ctrl=true: out-of-range lanes read 0 (matches zero padding).
#define DPP_WAVE_SHL1 0x130
#define DPP_WAVE_SHR1 0x138

template <int CTRL>
__device__ __forceinline__ float dpp_f(float x) {
    union { float f; int i; } u, o;
    u.f = x;
    o.i = __builtin_amdgcn_update_dpp(0, u.i, CTRL, 0xF, 0xF, true);
    return o.f;
}
template <int CTRL>
__device__ __forceinline__ __half2 dpp_h2(__half2 x) {
    union { __half2 h; int i; } u, o;
    u.h = x;
    o.i = __builtin_amdgcn_update_dpp(0, u.i, CTRL, 0xF, 0xF, true);
    return o.h;
}
#define SHL1F(x) dpp_f<DPP_WAVE_SHL1>(x)
#define SHR1F(x) dpp_f<DPP_WAVE_SHR1>(x)
#define SHL1H(x) dpp_h2<DPP_WAVE_SHL1>(x)
#define SHR1H(x) dpp_h2<DPP_WAVE_SHR1>(x)

// R7 champion body with the DS-shuffle horizontal tree replaced by a
// DPP-based VALU tree (zero DS ops in the main loop). Vertical: 11-deep
// half2 register ring with exact-cancellation f32 running sums.
__global__ __launch_bounds__(128) void fused_dpp(
    const float* __restrict__ pred, const float* __restrict__ target,
    float* __restrict__ ws_sq, float* __restrict__ ws_cos)
{
    __shared__ float red[4];
    const int tid  = threadIdx.x;
    const int wave = tid >> 6, lane = tid & 63;

    // bijective XCD-contiguous swizzle (1280 % 8 == 0)
    const int bid = (int)blockIdx.x;
    const int swz = (bid & 7) * (NBLK / 8) + (bid >> 3);

    const int task  = swz * 2 + wave;
    const int img   = task / (NSEG * NSTRIP);
    const int rem   = task % (NSEG * NSTRIP);
    const int seg   = rem / NSTRIP;
    const int strip = rem - seg * NSTRIP;

    const int y0   = seg * SEGV;
    const int col0 = strip * STRIPW - 6 + lane * 2;      // even
    const int colc = min(max(col0, 0), WW - 2);
    const float mx = (col0 >= 0 && col0 < WW) ? 1.f : 0.f;
    const bool vout = (lane >= 3) && (lane <= 60) && (col0 < WW);

    const long base = (long)img * (CC * HW);

    // prefetch row 0 (issue-early), depth-1 (VGPR-lean: R9/R11/R13 lesson)
    float2 P0, P1, P2, T0, T1, T2;
    {
        const int y  = y0 - RAD;
        const int yc = y < 0 ? 0 : y;
        const long off = base + (long)yc * WW + colc;
        P0 = *(const float2*)(pred + off);
        P1 = *(const float2*)(pred + off + HW);
        P2 = *(const float2*)(pred + off + 2 * HW);
        T0 = *(const float2*)(target + off);
        T1 = *(const float2*)(target + off + HW);
        T2 = *(const float2*)(target + off + 2 * HW);
    }

    __half2 ring0[11], ring1[11], ringT[11];   // (hd0,hp0), (hd1,hp1), (ht0,ht1)
    float Sd0=0.f, Sd1=0.f, Sp0=0.f, Sp1=0.f, St0=0.f, St1=0.f;
    float sq = 0.f, cosacc = 0.f;

    #pragma unroll
    for (int it = 0; it < NITER; ++it) {
        const int y = y0 - RAD + it;
        const float msk = (y >= 0 && y < HH) ? mx : 0.f;

        const float2 p0=P0, p1=P1, p2=P2, t0=T0, t1=T1, t2=T2;
        if (it + 1 < NITER) {                     // prefetch next row
            const int y2  = y0 - RAD + it + 1;
            const int yc2 = min(max(y2, 0), HH - 1);
            const long off2 = base + (long)yc2 * WW + colc;
            P0 = *(const float2*)(pred + off2);
            P1 = *(const float2*)(pred + off2 + HW);
            P2 = *(const float2*)(pred + off2 + 2 * HW);
            T0 = *(const float2*)(target + off2);
            T1 = *(const float2*)(target + off2 + HW);
            T2 = *(const float2*)(target + off2 + 2 * HW);
        }

        // per-pixel dot/pp/tt, masked (zero padding outside image)
        const float ad = (p0.x*t0.x + p1.x*t1.x + p2.x*t2.x) * msk;
        const float bd = (p0.y*t0.y + p1.y*t1.y + p2.y*t2.y) * msk;
        const float ap = (p0.x*p0.x + p1.x*p1.x + p2.x*p2.x) * msk;
        const float bp = (p0.y*p0.y + p1.y*p1.y + p2.y*p2.y) * msk;
        const float at = (t0.x*t0.x + t1.x*t1.x + t2.x*t2.x) * msk;
        const float bt = (t0.y*t0.y + t1.y*t1.y + t2.y*t2.y) * msk;

        // PSNR squared error from maps: sum_c (p-t)^2 = pp - 2*dot + tt
        if (it >= RAD && it < RAD + SEGV && vout) {
            sq += (ap + at - 2.f * ad) + (bp + bt - 2.f * bd);
        }

        // ---- horizontal 11-window via DPP wave shifts (VALU only) ----
        // pr pair-sums; w = sum_{j=0..4} pr_{i+j}; S5(i) = shl2(w);
        // h(2i) = shl3(B) + S5; h(2i+1) = S5 + shr3(A).
        __half2 h0dp, h1dp;
        {
            const __half2 Pk = __floats2half2_rn(ad + bd, ap + bp);
            const __half2 Ak = __floats2half2_rn(ad, ap);
            const __half2 Bk = __floats2half2_rn(bd, bp);
            __half2 w = Pk;
            w = __hadd2(Pk, SHR1H(w));
            w = __hadd2(Pk, SHR1H(w));
            w = __hadd2(Pk, SHR1H(w));
            w = __hadd2(Pk, SHR1H(w));            // sum pr_{i..i+4}
            const __half2 S5 = SHL1H(SHL1H(w));   // sum pr_{i-2..i+2}
            const __half2 eB = SHL1H(SHL1H(SHL1H(Bk)));
            const __half2 eA = SHR1H(SHR1H(SHR1H(Ak)));
            h0dp = __hadd2(eB, S5);
            h1dp = __hadd2(S5, eA);
        }
        __half2 hT;
        {
            const float pr = at + bt;
            float w = pr;
            w = pr + SHR1F(w);
            w = pr + SHR1F(w);
            w = pr + SHR1F(w);
            w = pr + SHR1F(w);
            const float S5 = SHL1F(SHL1F(w));
            const float eB = SHL1F(SHL1F(SHL1F(bt)));
            const float eA = SHR1F(SHR1F(SHR1F(at)));
            hT = __floats2half2_rn(eB + S5, S5 + eA);
        }

        // accumulate the QUANTIZED values -> ring subtract cancels exactly
        const float2 f0 = __half22float2(h0dp);
        const float2 f1 = __half22float2(h1dp);
        const float2 fT = __half22float2(hT);
        Sd0 += f0.x; Sp0 += f0.y;
        Sd1 += f1.x; Sp1 += f1.y;
        St0 += fT.x; St1 += fT.y;

        if (it >= 10) {
            if (vout) {
                cosacc += Sd0 * rsqrtf(fmaxf(Sp0 * St0, 1e-20f));
                cosacc += Sd1 * rsqrtf(fmaxf(Sp1 * St1, 1e-20f));
            }
            const float2 o0 = __half22float2(ring0[(it + 1) % 11]);
            const float2 o1 = __half22float2(ring1[(it + 1) % 11]);
            const float2 oT = __half22float2(ringT[(it + 1) % 11]);
            Sd0 -= o0.x; Sp0 -= o0.y;
            Sd1 -= o1.x; Sp1 -= o1.y;
            St0 -= oT.x; St1 -= oT.y;
        }
        ring0[it % 11] = h0dp;
        ring1[it % 11] = h1dp;
        ringT[it % 11] = hT;
    }

    // wave reduce -> block partials (DS shuffles OK here: once per wave)
    #pragma unroll
    for (int o = 32; o > 0; o >>= 1) {
        cosacc += __shfl_down(cosacc, o);
        sq     += __shfl_down(sq, o);
    }
    if (lane == 0) { red[wave] = cosacc; red[wave + 2] = sq; }
    __syncthreads();
    if (tid == 0) {
        ws_cos[swz] = red[0] + red[1];
        ws_sq [swz] = red[2] + red[3];
    }
}

// ---------------- finalize: 1280 sq + 1280 cos partials ----------------
__global__ __launch_bounds__(256) void finalize4(
    const float* __restrict__ ws_sq, const float* __restrict__ ws_cos,
    float* __restrict__ out)
{
    __shared__ float sq_b[16];
    __shared__ float cred[4];
    const int tid = threadIdx.x;

    // sq: 80 partials per image; 16 threads/image, 5 values each
    const int b = tid >> 4, j = tid & 15;
    float s = 0.f;
    #pragma unroll
    for (int k = 0; k < 5; ++k) s += ws_sq[b * 80 + j * 5 + k];
    #pragma unroll
    for (int o = 8; o > 0; o >>= 1) s += __shfl_down(s, o, 16);
    if (j == 0) sq_b[b] = s;

    float c = 0.f;
    #pragma unroll
    for (int k = 0; k < 5; ++k) c += ws_cos[tid + 256 * k];
    #pragma unroll
    for (int o = 32; o > 0; o >>= 1) c += __shfl_down(c, o);
    if ((tid & 63) == 0) cred[tid >> 6] = c;
    __syncthreads();

    if (tid == 0) {
        const float csum = cred[0] + cred[1] + cred[2] + cred[3];
        const float scale = 4.342944819032518f;   // 10 / ln(10)
        float lsum = 0.f;
        for (int bb = 0; bb < 16; ++bb)
            lsum += logf(sq_b[bb] / (float)(CC * HW) + 1e-8f);
        out[0] = scale * (lsum / (float)BB) + (1.f - csum / (float)(BB * HW));
    }
}

extern "C" void kernel_launch(void* const* d_in, const int* in_sizes, int n_in,
                              void* d_out, int out_size, void* d_ws, size_t ws_size,
                              hipStream_t stream)
{
    const float* pred   = (const float*)d_in[0];
    const float* target = (const float*)d_in[1];

    float* ws_sq  = (float*)d_ws;                        // 1280 floats
    float* ws_cos = (float*)((char*)d_ws + 8192);        // 1280 floats

    fused_dpp<<<dim3(NBLK), 128, 0, stream>>>(pred, target, ws_sq, ws_cos);
    finalize4<<<1, 256, 0, stream>>>(ws_sq, ws_cos, (float*)d_out);
}